// Round 1
// baseline (1080.698 us; speedup 1.0000x reference)
//
#include <hip/hip_runtime.h>
#include <hip/hip_bf16.h>
#include <stdint.h>

// Problem geometry (fixed by reference)
#define NQ 4096      // 64*8*8 query rows
#define NS 40960     // 32768 (s1) + 8192 (s_src)
#define CDIM 512
#define QT 128       // q rows per block (phase B)
#define SC 64        // s rows per chunk
#define NSPLIT 16    // s-dimension splits (grid.y)
#define SPER (NS / NSPLIT)   // 2560
#define NCHUNK (SPER / SC)   // 40

typedef float f32x4 __attribute__((ext_vector_type(4)));
typedef __bf16 bf16x8 __attribute__((ext_vector_type(8)));
typedef unsigned int u32x4 __attribute__((ext_vector_type(4)));

__device__ __forceinline__ unsigned short f2bf(float f) {
    uint32_t u = __builtin_bit_cast(uint32_t, f);
    u += 0x7fffu + ((u >> 16) & 1u);   // RNE (finite values only here)
    return (unsigned short)(u >> 16);
}

// CK-proven cast pattern: generic -> AS1/AS3 via uintptr (AS3 ptr is 32-bit offset)
__device__ __forceinline__ void async_load16(const void* g, void* l) {
    auto gp = reinterpret_cast<const __attribute__((address_space(1))) uint32_t*>(
        reinterpret_cast<uintptr_t>(g));
    auto lp = reinterpret_cast<__attribute__((address_space(3))) uint32_t*>(
        reinterpret_cast<uintptr_t>(l));
    __builtin_amdgcn_global_load_lds(gp, lp, 16 /*bytes, literal*/, 0, 0);
}

// ---------------- Phase A1: pool q (4x4 mean) + row-normalize -> bf16 ----------------
// grid 4096 (one block per output row), 256 threads, 2 channels/thread
__global__ __launch_bounds__(256) void pool_q_norm(const float* __restrict__ q,
                                                   unsigned short* __restrict__ qn) {
    int r = blockIdx.x;
    int b = r >> 6, h = (r >> 3) & 7, w = r & 7;
    int t = threadIdx.x, lane = t & 63, wid = t >> 6;
    float vals[2];
    float ss = 0.f;
#pragma unroll
    for (int e = 0; e < 2; ++e) {
        int c = 2 * t + e;
        const float* base = q + (((size_t)(b * 512 + c) * 32 + 4 * h) * 32 + 4 * w);
        float s = 0.f;
#pragma unroll
        for (int i = 0; i < 4; ++i) {
            float4 v = *(const float4*)(base + i * 32);
            s += (v.x + v.y) + (v.z + v.w);
        }
        s *= (1.f / 16.f);
        vals[e] = s;
        ss += s * s;
    }
#pragma unroll
    for (int o = 32; o > 0; o >>= 1) ss += __shfl_xor(ss, o, 64);
    __shared__ float red[4];
    if (lane == 0) red[wid] = ss;
    __syncthreads();
    float inv = 1.0f / sqrtf(red[0] + red[1] + red[2] + red[3]);
    ushort2 o2;
    o2.x = f2bf(vals[0] * inv);
    o2.y = f2bf(vals[1] * inv);
    *(ushort2*)(qn + (size_t)r * CDIM + 2 * t) = o2;
}

// ------- Phase A2: pool S at BOTH scales in one pass + row-normalize -> bf16 -------
// block = one s_src spatial cell (b,h2,w2): owns 1 src row + its 4 s1 rows, all channels.
// grid 8192, 256 threads, 2 channels/thread.
__global__ __launch_bounds__(256) void pool_s_norm(const float* __restrict__ S,
                                                   unsigned short* __restrict__ sn) {
    int rb = blockIdx.x;   // b*64 + h2*8 + w2
    int b = rb >> 6, h2 = (rb >> 3) & 7, w2 = rb & 7;
    int t = threadIdx.x, lane = t & 63, wid = t >> 6;
    float vals[2][5];
    float ss[5] = {0.f, 0.f, 0.f, 0.f, 0.f};
#pragma unroll
    for (int e = 0; e < 2; ++e) {
        int c = 2 * t + e;
        const float* base = S + (((size_t)(b * 512 + c) * 32 + 4 * h2) * 32 + 4 * w2);
        float4 v0 = *(const float4*)(base);
        float4 v1 = *(const float4*)(base + 32);
        float4 v2 = *(const float4*)(base + 64);
        float4 v3 = *(const float4*)(base + 96);
        float q00 = v0.x + v0.y + v1.x + v1.y;
        float q01 = v0.z + v0.w + v1.z + v1.w;
        float q10 = v2.x + v2.y + v3.x + v3.y;
        float q11 = v2.z + v2.w + v3.z + v3.w;
        vals[e][0] = q00 * 0.25f;   // s1 row (2h2+0, 2w2+0)
        vals[e][1] = q01 * 0.25f;   // (2h2+0, 2w2+1)
        vals[e][2] = q10 * 0.25f;   // (2h2+1, 2w2+0)
        vals[e][3] = q11 * 0.25f;   // (2h2+1, 2w2+1)
        vals[e][4] = (q00 + q01 + q10 + q11) * (1.f / 16.f);  // s_src row
#pragma unroll
        for (int k = 0; k < 5; ++k) ss[k] += vals[e][k] * vals[e][k];
    }
    __shared__ float red[5][4];
#pragma unroll
    for (int k = 0; k < 5; ++k) {
        float v = ss[k];
#pragma unroll
        for (int o = 32; o > 0; o >>= 1) v += __shfl_xor(v, o, 64);
        if (lane == 0) red[k][wid] = v;
    }
    __syncthreads();
    float inv[5];
#pragma unroll
    for (int k = 0; k < 5; ++k)
        inv[k] = 1.0f / sqrtf(red[k][0] + red[k][1] + red[k][2] + red[k][3]);
    int rows[5];
#pragma unroll
    for (int i = 0; i < 2; ++i)
#pragma unroll
        for (int j = 0; j < 2; ++j)
            rows[i * 2 + j] = b * 256 + (2 * h2 + i) * 16 + (2 * w2 + j);
    rows[4] = 32768 + rb;
#pragma unroll
    for (int k = 0; k < 5; ++k) {
        ushort2 o2;
        o2.x = f2bf(vals[0][k] * inv[k]);
        o2.y = f2bf(vals[1][k] * inv[k]);
        *(ushort2*)(sn + (size_t)rows[k] * CDIM + 2 * t) = o2;
    }
}

// ---------------- Phase B: bf16 MFMA sim GEMM + fused per-row top-15 ----------------
// grid (32 q-tiles, 16 s-splits), 512 threads = 8 waves. Wave w owns q rows w*16..+15.
__global__ __launch_bounds__(512, 2) void sim_topk(const unsigned short* __restrict__ qn,
                                                   const unsigned short* __restrict__ sn,
                                                   float* __restrict__ partial) {
    __shared__ unsigned short Bs[SC * CDIM];   // 64KB: 64 rows x 1KB, XOR-swizzled
    __shared__ float simC[QT][69];             // pad 69: conflict-free column scans
    __shared__ float topk[QT * 4 * 15];        // per (row, quarter) top-15
    int tid = threadIdx.x, lane = tid & 63, wid = tid >> 6;
    int qbase = blockIdx.x * QT;
    int sbase = blockIdx.y * SPER;

    // A fragments: wave's 16 q rows, full K=512, in registers (64 VGPR)
    bf16x8 a[16];
    {
        int qrow = qbase + wid * 16 + (lane & 15);
        const unsigned short* qp = qn + (size_t)qrow * CDIM + ((lane >> 4) * 8);
#pragma unroll
        for (int ks = 0; ks < 16; ++ks)
            a[ks] = __builtin_bit_cast(bf16x8, *(const u32x4*)(qp + ks * 32));
    }

    int srow = tid & 127, quar = tid >> 7;   // scan ownership
    float* myk = &topk[(srow * 4 + quar) * 15];
#pragma unroll
    for (int i = 0; i < 15; ++i) myk[i] = -2.0f;   // below min cosine
    float minv = -2.0f;
    int mini = 0;

    char* BsB = (char*)Bs;

    for (int ch = 0; ch < NCHUNK; ++ch) {
        // Stage 64 s-rows -> LDS (linear dest, source pre-swizzled by ((row&7)<<4))
#pragma unroll
        for (int i = 0; i < 8; ++i) {
            int row = i * 8 + wid;                       // wave-uniform
            int srcrow = sbase + ch * SC + row;
            int inner = (lane * 16) ^ ((row & 7) << 4);  // per-lane global src offset
            async_load16((const char*)sn + ((size_t)srcrow << 10) + inner,
                         BsB + row * 1024);
        }
        __syncthreads();   // drains vmcnt: Bs ready; also orders prev scan before simC write

        f32x4 acc[4];
#pragma unroll
        for (int cg = 0; cg < 4; ++cg) acc[cg] = (f32x4){0.f, 0.f, 0.f, 0.f};
#pragma unroll
        for (int ks = 0; ks < 16; ++ks) {
            bf16x8 bfr[4];
#pragma unroll
            for (int cg = 0; cg < 4; ++cg) {
                int row = cg * 16 + (lane & 15);
                int inner = ((ks * 64) | ((lane >> 4) * 16)) ^ ((row & 7) << 4);
                bfr[cg] = __builtin_bit_cast(bf16x8, *(const u32x4*)(BsB + row * 1024 + inner));
            }
#pragma unroll
            for (int cg = 0; cg < 4; ++cg)
                acc[cg] = __builtin_amdgcn_mfma_f32_16x16x32_bf16(a[ks], bfr[cg], acc[cg], 0, 0, 0);
        }
        // C layout (verified m89/m91): col = lane&15, row = (lane>>4)*4 + reg
#pragma unroll
        for (int cg = 0; cg < 4; ++cg)
#pragma unroll
            for (int r = 0; r < 4; ++r)
                simC[wid * 16 + (lane >> 4) * 4 + r][cg * 16 + (lane & 15)] = acc[cg][r];
        __syncthreads();   // simC complete; Bs free for next stage

        // Per-(row,quarter) streaming top-15 (replace-min, threshold in register)
#pragma unroll
        for (int j = 0; j < 16; ++j) {
            float v = simC[srow][quar * 16 + j];
            if (v > minv) {
                myk[mini] = v;
                minv = myk[0]; mini = 0;
#pragma unroll
                for (int i2 = 1; i2 < 15; ++i2) {
                    float u = myk[i2];
                    if (u < minv) { minv = u; mini = i2; }
                }
            }
        }
    }
    // Emit 15 candidates per (row, quarter): layout partial[qrow][split][quar][15]
    float* dst = partial + (((size_t)(qbase + srow) * NSPLIT + blockIdx.y) * 60 + quar * 15);
#pragma unroll
    for (int i = 0; i < 15; ++i) dst[i] = myk[i];
}

// ---------------- Final: merge 960 candidates/row -> top15 -> LSE/top4 loss ----------------
__global__ __launch_bounds__(64) void topk_loss(const float* __restrict__ partial,
                                                float* __restrict__ accum) {
    int r = blockIdx.x, t = threadIdx.x;
    __shared__ float sc[960];
    __shared__ float top[15];
#pragma unroll
    for (int i = 0; i < 15; ++i) sc[t + 64 * i] = partial[(size_t)r * 960 + t + 64 * i];
    __syncthreads();
    for (int round = 0; round < 15; ++round) {
        float m = -1e30f;
        int mi = 0;
#pragma unroll
        for (int i = 0; i < 15; ++i) {
            float v = sc[t + 64 * i];
            if (v > m) { m = v; mi = t + 64 * i; }
        }
#pragma unroll
        for (int o = 32; o > 0; o >>= 1) {
            float om = __shfl_down(m, o, 64);
            int oi = __shfl_down(mi, o, 64);
            if (om > m) { m = om; mi = oi; }
        }
        if (t == 0) { top[round] = m; sc[mi] = -1e30f; }
        __syncthreads();
    }
    if (t == 0) {
        float m = top[0], s = 0.f;
#pragma unroll
        for (int i = 0; i < 15; ++i) s += expf(top[i] - m);
        float lse = m + logf(s);
        float loss = lse - 0.25f * (top[0] + top[1] + top[2] + top[3]);
        atomicAdd(accum, loss);
    }
}

__global__ void finalize_out(const float* __restrict__ accum, float* __restrict__ out) {
    out[0] = accum[0] * (1.0f / (float)NQ);
}

// ---------------- Launch ----------------
extern "C" void kernel_launch(void* const* d_in, const int* in_sizes, int n_in,
                              void* d_out, int out_size, void* d_ws, size_t ws_size,
                              hipStream_t stream) {
    (void)in_sizes; (void)n_in; (void)out_size; (void)ws_size;
    const float* q = (const float*)d_in[0];
    const float* S = (const float*)d_in[1];
    char* ws = (char*)d_ws;
    unsigned short* qn = (unsigned short*)ws;                        // 4,194,304 B
    unsigned short* sn = (unsigned short*)(ws + 4194304);            // 41,943,040 B
    float* partial = (float*)(ws + 4194304 + 41943040);              // 15,728,640 B
    float* accum   = (float*)(ws + 4194304 + 41943040 + 15728640);   // 4 B

    hipMemsetAsync(accum, 0, 4, stream);
    pool_q_norm<<<NQ, 256, 0, stream>>>(q, qn);
    pool_s_norm<<<8192, 256, 0, stream>>>(S, sn);
    dim3 gb(NQ / QT, NSPLIT);
    sim_topk<<<gb, 512, 0, stream>>>(qn, sn, partial);
    topk_loss<<<NQ, 64, 0, stream>>>(partial, accum);
    finalize_out<<<1, 1, 0, stream>>>(accum, (float*)d_out);
}

// Round 2
// 505.881 us; speedup vs baseline: 2.1363x; 2.1363x over previous
//
#include <hip/hip_runtime.h>
#include <hip/hip_bf16.h>
#include <stdint.h>

// Problem geometry (fixed by reference)
#define NQ 4096      // 64*8*8 query rows
#define NS 40960     // 32768 (s1) + 8192 (s_src)
#define CDIM 512
#define QT 256       // q rows per block (phase B): 8 waves x 32 q
#define SC 64        // s rows per chunk
#define NSPLIT 16    // s-dimension splits (grid.y)
#define SPER (NS / NSPLIT)   // 2560
#define NCHUNK (SPER / SC)   // 40
#define NCAND 480    // per-row candidates: 16 splits * 2 sublanes * 15

typedef float f32x16 __attribute__((ext_vector_type(16)));
typedef __bf16 bf16x8 __attribute__((ext_vector_type(8)));
typedef unsigned int u32x4 __attribute__((ext_vector_type(4)));

__device__ __forceinline__ unsigned short f2bf(float f) {
    uint32_t u = __builtin_bit_cast(uint32_t, f);
    u += 0x7fffu + ((u >> 16) & 1u);   // RNE (finite values only here)
    return (unsigned short)(u >> 16);
}

// CK-proven cast pattern: generic -> AS1/AS3 via uintptr
__device__ __forceinline__ void async_load16(const void* g, void* l) {
    auto gp = reinterpret_cast<const __attribute__((address_space(1))) uint32_t*>(
        reinterpret_cast<uintptr_t>(g));
    auto lp = reinterpret_cast<__attribute__((address_space(3))) uint32_t*>(
        reinterpret_cast<uintptr_t>(l));
    __builtin_amdgcn_global_load_lds(gp, lp, 16 /*bytes, literal*/, 0, 0);
}

// ---------------- Phase A1: pool q (4x4 mean) + row-normalize -> bf16 ----------------
// grid 4096, 256 threads, 2 channels/thread. XCD-chunked swizzle: the 64 spatial
// blocks of one b co-locate on one XCD so the 16B/lane strided reads share L2 lines.
__global__ __launch_bounds__(256) void pool_q_norm(const float* __restrict__ q,
                                                   unsigned short* __restrict__ qn) {
    int i0 = blockIdx.x;
    int r = (i0 & 7) * 512 + (i0 >> 3);   // bijective: 4096 = 8 * 512
    int b = r >> 6, h = (r >> 3) & 7, w = r & 7;
    int t = threadIdx.x, lane = t & 63, wid = t >> 6;
    float vals[2];
    float ss = 0.f;
#pragma unroll
    for (int e = 0; e < 2; ++e) {
        int c = 2 * t + e;
        const float* base = q + (((size_t)(b * 512 + c) * 32 + 4 * h) * 32 + 4 * w);
        float s = 0.f;
#pragma unroll
        for (int i = 0; i < 4; ++i) {
            float4 v = *(const float4*)(base + i * 32);
            s += (v.x + v.y) + (v.z + v.w);
        }
        s *= (1.f / 16.f);
        vals[e] = s;
        ss += s * s;
    }
#pragma unroll
    for (int o = 32; o > 0; o >>= 1) ss += __shfl_xor(ss, o, 64);
    __shared__ float red[4];
    if (lane == 0) red[wid] = ss;
    __syncthreads();
    float inv = 1.0f / sqrtf(red[0] + red[1] + red[2] + red[3]);
    ushort2 o2;
    o2.x = f2bf(vals[0] * inv);
    o2.y = f2bf(vals[1] * inv);
    *(ushort2*)(qn + (size_t)r * CDIM + 2 * t) = o2;
}

// ------- Phase A2: pool S at BOTH scales in one pass + row-normalize -> bf16 -------
__global__ __launch_bounds__(256) void pool_s_norm(const float* __restrict__ S,
                                                   unsigned short* __restrict__ sn) {
    int i0 = blockIdx.x;
    int rb = (i0 & 7) * 1024 + (i0 >> 3);   // bijective: 8192 = 8 * 1024
    int b = rb >> 6, h2 = (rb >> 3) & 7, w2 = rb & 7;
    int t = threadIdx.x, lane = t & 63, wid = t >> 6;
    float vals[2][5];
    float ss[5] = {0.f, 0.f, 0.f, 0.f, 0.f};
#pragma unroll
    for (int e = 0; e < 2; ++e) {
        int c = 2 * t + e;
        const float* base = S + (((size_t)(b * 512 + c) * 32 + 4 * h2) * 32 + 4 * w2);
        float4 v0 = *(const float4*)(base);
        float4 v1 = *(const float4*)(base + 32);
        float4 v2 = *(const float4*)(base + 64);
        float4 v3 = *(const float4*)(base + 96);
        float q00 = v0.x + v0.y + v1.x + v1.y;
        float q01 = v0.z + v0.w + v1.z + v1.w;
        float q10 = v2.x + v2.y + v3.x + v3.y;
        float q11 = v2.z + v2.w + v3.z + v3.w;
        vals[e][0] = q00 * 0.25f;
        vals[e][1] = q01 * 0.25f;
        vals[e][2] = q10 * 0.25f;
        vals[e][3] = q11 * 0.25f;
        vals[e][4] = (q00 + q01 + q10 + q11) * (1.f / 16.f);
#pragma unroll
        for (int k = 0; k < 5; ++k) ss[k] += vals[e][k] * vals[e][k];
    }
    __shared__ float red[5][4];
#pragma unroll
    for (int k = 0; k < 5; ++k) {
        float v = ss[k];
#pragma unroll
        for (int o = 32; o > 0; o >>= 1) v += __shfl_xor(v, o, 64);
        if (lane == 0) red[k][wid] = v;
    }
    __syncthreads();
    float inv[5];
#pragma unroll
    for (int k = 0; k < 5; ++k)
        inv[k] = 1.0f / sqrtf(red[k][0] + red[k][1] + red[k][2] + red[k][3]);
    int rows[5];
#pragma unroll
    for (int i = 0; i < 2; ++i)
#pragma unroll
        for (int j = 0; j < 2; ++j)
            rows[i * 2 + j] = b * 256 + (2 * h2 + i) * 16 + (2 * w2 + j);
    rows[4] = 32768 + rb;
#pragma unroll
    for (int k = 0; k < 5; ++k) {
        ushort2 o2;
        o2.x = f2bf(vals[0][k] * inv[k]);
        o2.y = f2bf(vals[1][k] * inv[k]);
        *(ushort2*)(sn + (size_t)rows[k] * CDIM + 2 * t) = o2;
    }
}

// ---------------- Phase B: swapped-operand 32x32x16 MFMA + in-register top-15 ----------------
// grid (16 q-tiles, 16 s-splits) = 256 blocks = 1/CU. 512 threads = 8 waves.
// D[s][q]: A = s rows (from LDS, dbuf), B = q (32 rows/wave, 128 VGPR).
// C layout (m74/m101): col = lane&31 -> each lane owns ONE q-row; rows = s.
// Per-lane top-15 lives in 15 registers (sorted desc, unrolled max/min insert).
__global__ __launch_bounds__(512, 2) void sim_topk(const unsigned short* __restrict__ qn,
                                                   const unsigned short* __restrict__ sn,
                                                   float* __restrict__ partial) {
    __shared__ unsigned short Bs[2][SC * CDIM];   // 2 x 64KB, XOR-swizzled rows
    int tid = threadIdx.x, lane = tid & 63, wid = tid >> 6;
    int qbase = blockIdx.x * QT;
    int sbase = blockIdx.y * SPER;
    char* BsB = (char*)&Bs[0][0];
    const char* snB = (const char*)sn;

    // B fragments (q side): wave's 32 q rows, full K=512. k = ks*16 + (lane>>5)*8 + e.
    bf16x8 b[32];
    {
        int qrow = qbase + wid * 32 + (lane & 31);
        const unsigned short* qp = qn + (size_t)qrow * CDIM + ((lane >> 5) * 8);
#pragma unroll
        for (int ks = 0; ks < 32; ++ks)
            b[ks] = __builtin_bit_cast(bf16x8, *(const u32x4*)(qp + ks * 16));
    }

    float r[15];
#pragma unroll
    for (int i = 0; i < 15; ++i) r[i] = -2.0f;   // below min cosine

    auto stage = [&](int ch, int buf) {
#pragma unroll
        for (int i = 0; i < 8; ++i) {
            int row = i * 8 + wid;                       // wave-uniform
            size_t srcoff = ((size_t)(sbase + ch * SC + row) << 10)
                          + (size_t)((lane * 16) ^ ((row & 7) << 4));
            async_load16(snB + srcoff, BsB + buf * 65536 + row * 1024);
        }
    };

    // s-frag addressing (A side): row = sg*32 + (lane&31); k-bytes = ks*32 + (lane>>5)*16
    int rlo = lane & 31;
    int swz = (rlo & 7) << 4;                 // (32+rlo)&7 == rlo&7: same swizzle both sgs
    int base0 = rlo * 1024, base1 = (32 + rlo) * 1024;
    int innerbase = (lane >> 5) * 16;

    stage(0, 0);
    for (int ch = 0; ch < NCHUNK; ++ch) {
        int nxt = (ch + 1) % NCHUNK;          // wrap: last iter re-stages chunk 0 (harmless)
        stage(nxt, (ch + 1) & 1);
        asm volatile("s_waitcnt vmcnt(8)" ::: "memory");   // my 8 loads for chunk ch landed
        __builtin_amdgcn_s_barrier();                      // everyone's landed
        const char* B0 = BsB + (ch & 1) * 65536;
        f32x16 acc0 = {0.f}, acc1 = {0.f};
        __builtin_amdgcn_s_setprio(1);
#pragma unroll
        for (int ks = 0; ks < 32; ++ks) {
            int inner = (ks * 32 + innerbase) ^ swz;
            bf16x8 a0 = __builtin_bit_cast(bf16x8, *(const u32x4*)(B0 + base0 + inner));
            bf16x8 a1 = __builtin_bit_cast(bf16x8, *(const u32x4*)(B0 + base1 + inner));
            acc0 = __builtin_amdgcn_mfma_f32_32x32x16_bf16(a0, b[ks], acc0, 0, 0, 0);
            acc1 = __builtin_amdgcn_mfma_f32_32x32x16_bf16(a1, b[ks], acc1, 0, 0, 0);
        }
        __builtin_amdgcn_s_setprio(0);
        __builtin_amdgcn_s_barrier();   // all ds_reads of this buffer retired -> stageable

        // In-register streaming top-15 (sorted desc; static indices only)
#pragma unroll
        for (int sg = 0; sg < 2; ++sg) {
#pragma unroll
            for (int e = 0; e < 16; ++e) {
                float v = (sg == 0) ? acc0[e] : acc1[e];
                if (v > r[14]) {
#pragma unroll
                    for (int i = 0; i < 15; ++i) {
                        float mx = fmaxf(r[i], v);
                        v = fminf(r[i], v);
                        r[i] = mx;
                    }
                }
            }
        }
    }

    // Emit 15 candidates per lane: partial[qrow][split][sub][15], sub = lane>>5
    int qrow = qbase + wid * 32 + (lane & 31);
    float* dst = partial + (((size_t)qrow * NSPLIT + blockIdx.y) * 30 + (lane >> 5) * 15);
#pragma unroll
    for (int i = 0; i < 15; ++i) dst[i] = r[i];
}

// ---------------- Final: merge 480 candidates/row -> top15 -> LSE/top4 loss ----------------
__global__ __launch_bounds__(64) void topk_loss(const float* __restrict__ partial,
                                                float* __restrict__ accum) {
    int r = blockIdx.x, t = threadIdx.x;
    __shared__ float sc[512];
    __shared__ float top[15];
#pragma unroll
    for (int i = 0; i < 8; ++i) {
        int idx = t + 64 * i;
        sc[idx] = (idx < NCAND) ? partial[(size_t)r * NCAND + idx] : -1e30f;
    }
    __syncthreads();
    for (int round = 0; round < 15; ++round) {
        float m = -1e30f;
        int mi = 0;
#pragma unroll
        for (int i = 0; i < 8; ++i) {
            float v = sc[t + 64 * i];
            if (v > m) { m = v; mi = t + 64 * i; }
        }
#pragma unroll
        for (int o = 32; o > 0; o >>= 1) {
            float om = __shfl_down(m, o, 64);
            int oi = __shfl_down(mi, o, 64);
            if (om > m) { m = om; mi = oi; }
        }
        if (t == 0) { top[round] = m; sc[mi] = -1e30f; }
        __syncthreads();
    }
    if (t == 0) {
        float m = top[0], s = 0.f;
#pragma unroll
        for (int i = 0; i < 15; ++i) s += expf(top[i] - m);
        float lse = m + logf(s);
        float loss = lse - 0.25f * (top[0] + top[1] + top[2] + top[3]);
        atomicAdd(accum, loss);
    }
}

__global__ void finalize_out(const float* __restrict__ accum, float* __restrict__ out) {
    out[0] = accum[0] * (1.0f / (float)NQ);
}

// ---------------- Launch ----------------
extern "C" void kernel_launch(void* const* d_in, const int* in_sizes, int n_in,
                              void* d_out, int out_size, void* d_ws, size_t ws_size,
                              hipStream_t stream) {
    (void)in_sizes; (void)n_in; (void)out_size; (void)ws_size;
    const float* q = (const float*)d_in[0];
    const float* S = (const float*)d_in[1];
    char* ws = (char*)d_ws;
    unsigned short* qn = (unsigned short*)ws;                        // 4,194,304 B
    unsigned short* sn = (unsigned short*)(ws + 4194304);            // 41,943,040 B
    float* partial = (float*)(ws + 4194304 + 41943040);              // 7,864,320 B
    float* accum   = (float*)(ws + 4194304 + 41943040 + 7864320);    // 4 B

    hipMemsetAsync(accum, 0, 4, stream);
    pool_q_norm<<<NQ, 256, 0, stream>>>(q, qn);
    pool_s_norm<<<8192, 256, 0, stream>>>(S, sn);
    dim3 gb(NQ / QT, NSPLIT);
    sim_topk<<<gb, 512, 0, stream>>>(qn, sn, partial);
    topk_loss<<<NQ, 64, 0, stream>>>(partial, accum);
    finalize_out<<<1, 1, 0, stream>>>(accum, (float*)d_out);
}